// Round 6
// baseline (287.958 us; speedup 1.0000x reference)
//
#include <hip/hip_runtime.h>
#include <hip/hip_bf16.h>

#define NTOK 49
#define CDIM 128
#define C3   384
#define NHEAD 4
#define HDIM 32
#define LOG2E 1.4426950408889634f
#define SC2   (0.17677669529663687f * 1.4426950408889634f)
#define QS2 132   // x/O tile row stride, elems (264 B rows; known-good bank spread)
#define TSV 52    // per-wave vT token stride (104 B rows)
#define VTW 3328  // per-wave vT bytes: 32*52*2

typedef __attribute__((ext_vector_type(8))) __bf16 bf16x8;
typedef __attribute__((ext_vector_type(4))) __bf16 bf16x4;
typedef __attribute__((ext_vector_type(4))) float f32x4;

__device__ __forceinline__ f32x4 mfma32(bf16x8 a, bf16x8 b, f32x4 c) {
  return __builtin_amdgcn_mfma_f32_16x16x32_bf16(a, b, c, 0, 0, 0);
}
// K=16 semantics emulated on x32: j=0..3 real, j=4..7 dead (one operand zero-padded,
// the other dup'd so the dead half is defined-finite).
__device__ __forceinline__ bf16x8 dup8(bf16x4 t) {
  uint2 w = __builtin_bit_cast(uint2, t);
  uint4 r; r.x = w.x; r.y = w.y; r.z = w.x; r.w = w.y;
  return __builtin_bit_cast(bf16x8, r);
}
__device__ __forceinline__ bf16x8 zpad8(bf16x4 t) {
  uint2 w = __builtin_bit_cast(uint2, t);
  uint4 r; r.x = w.x; r.y = w.y; r.z = 0u; r.w = 0u;
  return __builtin_bit_cast(bf16x8, r);
}
__device__ __forceinline__ unsigned pkbf(float lo, float hi) {
  unsigned short a = __builtin_bit_cast(unsigned short, (__bf16)lo);
  unsigned short b = __builtin_bit_cast(unsigned short, (__bf16)hi);
  return ((unsigned)b << 16) | (unsigned)a;
}

// ws layout (bytes):
//   qkvT  __bf16[384][128] @ 0       qkvT[n][k] = qkv_w[k][n]; q rows pre-scaled by SCALE*LOG2E
//   projT __bf16[128][128] @ 98304
//   blut  float [4][64][64]@ 131072  rel-bias LUT [h][q][k] * LOG2E, k>=49 -> -1.44e30

__global__ __launch_bounds__(256) void prep_kernel(
    const float* __restrict__ qkv_w, const float* __restrict__ proj_w,
    const float* __restrict__ bias_table,
    __bf16* __restrict__ qkvT, __bf16* __restrict__ projT, float* __restrict__ blut)
{
  int o = blockIdx.x * 256 + threadIdx.x;
  if (o < CDIM * C3) {
    int k = o / C3, n = o - k * C3;
    float v = qkv_w[o];
    if (n < CDIM) v *= SC2;                // fold softmax scale AND log2e into q weights
    qkvT[n * CDIM + k] = (__bf16)v;
  } else if (o < CDIM * C3 + CDIM * CDIM) {
    int o2 = o - CDIM * C3;
    int k = o2 >> 7, n = o2 & 127;
    projT[n * CDIM + k] = (__bf16)proj_w[o2];
  } else if (o < CDIM * C3 + CDIM * CDIM + NHEAD * 64 * 64) {
    int t3 = o - (CDIM * C3 + CDIM * CDIM);
    int hh = t3 >> 12, r = (t3 >> 6) & 63, c = t3 & 63;
    float v;
    if (c >= NTOK) v = -1e30f;             // softmax mask for padded key columns
    else if (r >= NTOK) v = 0.0f;          // padded query rows: finite, never stored
    else {
      int idx = (r / 7 - c / 7 + 6) * 13 + (r % 7 - c % 7 + 6);
      v = bias_table[idx * NHEAD + hh];
    }
    blut[t3] = v * LOG2E;                  // fold log2e -> exp2 in kernel
  }
}

// 256 threads = 4 waves; wave h owns head h end-to-end (its 32 q/k/v channels).
// K,Q transposed in-register (per-tile, inside the producer loops); V via wave-local
// LDS strip; P in regs. NO occupancy floor: the (N,k) launch_bounds cap has produced
// forced spill (33-118 MB scratch traffic) in every round it was used; occupancy was
// measured irrelevant (r0 42% vs r1 59% -> same time), spill costs 23-70 us.
__global__ __launch_bounds__(256) void attn_kernel(
    const float* __restrict__ x, const float* __restrict__ qkv_b,
    const float* __restrict__ proj_b, const char* __restrict__ ws,
    float* __restrict__ out)
{
  __shared__ __align__(16) char smem[26248];
  char* xo_ = smem;                        // [49][132] bf16: x tile, later O tile

  const __bf16* qkvT  = (const __bf16*)ws;
  const __bf16* projT = (const __bf16*)(ws + 98304);
  const float*  blut  = (const float*)(ws + 131072);

  const int tid  = threadIdx.x;
  const int wave = tid >> 6;               // 0..3 == head
  const int lane = tid & 63;
  const int l15  = lane & 15;
  const int lg   = lane >> 4;
  const int hc   = wave * HDIM;            // this wave's 32-channel base
  __bf16* vTw = (__bf16*)(smem + 12936 + wave * VTW);  // [32][52] V^T strip

  const int win = blockIdx.x;
  const int b  = win >> 6;
  const int wh = (win >> 3) & 7;
  const int ww = win & 7;
  const float* xbase = x + (((b * 56) + wh * 7) * 56 + ww * 7) * CDIM;

  // per-lane clamped row byte-bases into the 132-stride tile
  int rb[4];
  #pragma unroll
  for (int mt = 0; mt < 4; ++mt) {
    int t = mt * 16 + l15; if (t > 48) t = 48;
    rb[mt] = t * (QS2 * 2);
  }

  // ---- phase 0: stage x rows 0..48 into LDS bf16 [49][132] ----
  #pragma unroll
  for (int p = 0; p < 4; ++p) {
    int L = p * 256 + tid;
    if (L < 784) {                          // 49 rows * 16 chunks
      int r = L >> 4, c = L & 15;
      const float* g = xbase + ((r / 7) * 56 + (r % 7)) * CDIM + c * 8;
      f32x4 x0 = *(const f32x4*)g;
      f32x4 x1 = *(const f32x4*)(g + 4);
      bf16x8 v8;
      v8[0] = (__bf16)x0[0]; v8[1] = (__bf16)x0[1]; v8[2] = (__bf16)x0[2]; v8[3] = (__bf16)x0[3];
      v8[4] = (__bf16)x1[0]; v8[5] = (__bf16)x1[1]; v8[6] = (__bf16)x1[2]; v8[7] = (__bf16)x1[3];
      *(bf16x8*)(xo_ + r * (QS2 * 2) + c * 16) = v8;
    }
  }

  __syncthreads();   // [1] x tile ready

  // ---- K-pass: per-tile compute + immediate in-register transpose -> akf ----
  bf16x8 akf[4];           // QK A-frags: lane(tok=nt*16+l15, lg): elem j -> ch hc+lg*8+j
  {
    bf16x8 aw[2][4];
    #pragma unroll
    for (int ct = 0; ct < 2; ++ct)
      #pragma unroll
      for (int kt = 0; kt < 4; ++kt)
        aw[ct][kt] = *(const bf16x8*)(qkvT + (CDIM + hc + ct * 16 + l15) * CDIM + kt * 32 + lg * 8);
    f32x4 kb[2];
    kb[0] = *(const f32x4*)(qkv_b + CDIM + hc + lg * 4);
    kb[1] = *(const f32x4*)(qkv_b + CDIM + hc + 16 + lg * 4);
    #pragma unroll
    for (int mt = 0; mt < 4; ++mt) {
      bf16x8 a[4];
      #pragma unroll
      for (int kt = 0; kt < 4; ++kt)
        a[kt] = *(const bf16x8*)(xo_ + rb[mt] + kt * 64 + lg * 16);
      unsigned pk[2][2];   // [ct][t]: K[ch=hc+ct*16+lg*4+2t(+1)][tok=mt*16+l15]
      #pragma unroll
      for (int ct = 0; ct < 2; ++ct) {
        f32x4 ck; ck[0]=0.f; ck[1]=0.f; ck[2]=0.f; ck[3]=0.f;
        #pragma unroll
        for (int kt = 0; kt < 4; ++kt) ck = mfma32(aw[ct][kt], a[kt], ck);
        pk[ct][0] = pkbf(ck[0] + kb[ct][0], ck[1] + kb[ct][1]);
        pk[ct][1] = pkbf(ck[2] + kb[ct][2], ck[3] + kb[ct][3]);
      }
      // transpose to A-frag layout (8 shfl + 4 sel; r3/r5-verified mapping)
      unsigned w[4];
      #pragma unroll
      for (int d = 0; d < 4; ++d) {
        int srcl = ((lg & 1) * 2 + (d >> 1)) * 16 + l15;
        unsigned w0 = __shfl(pk[0][d & 1], srcl);
        unsigned w1 = __shfl(pk[1][d & 1], srcl);
        w[d] = (lane >= 32) ? w1 : w0;
      }
      uint4 u; u.x = w[0]; u.y = w[1]; u.z = w[2]; u.w = w[3];
      akf[mt] = __builtin_bit_cast(bf16x8, u);
    }
  }

  // ---- V-pass: V^T[ch][tok] into wave-local LDS strip (same-wave RAW, no barrier) ----
  {
    bf16x8 aw[2][4];
    #pragma unroll
    for (int ct = 0; ct < 2; ++ct)
      #pragma unroll
      for (int kt = 0; kt < 4; ++kt)
        aw[ct][kt] = *(const bf16x8*)(qkvT + (2 * CDIM + hc + ct * 16 + l15) * CDIM + kt * 32 + lg * 8);
    f32x4 vb[2];
    vb[0] = *(const f32x4*)(qkv_b + 2 * CDIM + hc + lg * 4);
    vb[1] = *(const f32x4*)(qkv_b + 2 * CDIM + hc + 16 + lg * 4);
    #pragma unroll
    for (int mt = 0; mt < 4; ++mt) {
      const int tok = mt * 16 + l15;
      bf16x8 a[4];
      #pragma unroll
      for (int kt = 0; kt < 4; ++kt)
        a[kt] = *(const bf16x8*)(xo_ + rb[mt] + kt * 64 + lg * 16);
      f32x4 cv[2];
      #pragma unroll
      for (int ct = 0; ct < 2; ++ct) {
        cv[ct][0]=0.f; cv[ct][1]=0.f; cv[ct][2]=0.f; cv[ct][3]=0.f;
        #pragma unroll
        for (int kt = 0; kt < 4; ++kt) cv[ct] = mfma32(aw[ct][kt], a[kt], cv[ct]);
      }
      if (tok <= 48) {
        #pragma unroll
        for (int ct = 0; ct < 2; ++ct)
          #pragma unroll
          for (int i = 0; i < 4; ++i)
            vTw[(ct * 16 + lg * 4 + i) * TSV + tok] = (__bf16)(cv[ct][i] + vb[ct][i]);
      } else if (tok <= 51) {               // zero cols 49..51 (clamped PV b64 reach)
        #pragma unroll
        for (int ct = 0; ct < 2; ++ct)
          #pragma unroll
          for (int i = 0; i < 4; ++i)
            vTw[(ct * 16 + lg * 4 + i) * TSV + tok] = (__bf16)0.0f;
      }
    }
  }

  // ---- Q-pass: per-tile compute + immediate transpose -> bqf (B-frag per q-tile) ----
  bf16x8 bqf[4];
  {
    bf16x8 aw[2][4];
    #pragma unroll
    for (int ct = 0; ct < 2; ++ct)
      #pragma unroll
      for (int kt = 0; kt < 4; ++kt)
        aw[ct][kt] = *(const bf16x8*)(qkvT + (hc + ct * 16 + l15) * CDIM + kt * 32 + lg * 8);
    f32x4 qb[2];
    qb[0] = *(const f32x4*)(qkv_b + hc + lg * 4);
    qb[1] = *(const f32x4*)(qkv_b + hc + 16 + lg * 4);
    #pragma unroll
    for (int ct = 0; ct < 2; ++ct)
      #pragma unroll
      for (int i = 0; i < 4; ++i) qb[ct][i] *= SC2;   // match pre-scaled q weights
    #pragma unroll
    for (int mt = 0; mt < 4; ++mt) {
      bf16x8 a[4];
      #pragma unroll
      for (int kt = 0; kt < 4; ++kt)
        a[kt] = *(const bf16x8*)(xo_ + rb[mt] + kt * 64 + lg * 16);
      unsigned pk[2][2];
      #pragma unroll
      for (int ct = 0; ct < 2; ++ct) {
        f32x4 qc; qc[0]=0.f; qc[1]=0.f; qc[2]=0.f; qc[3]=0.f;
        #pragma unroll
        for (int kt = 0; kt < 4; ++kt) qc = mfma32(aw[ct][kt], a[kt], qc);
        pk[ct][0] = pkbf(qc[0] + qb[ct][0], qc[1] + qb[ct][1]);
        pk[ct][1] = pkbf(qc[2] + qb[ct][2], qc[3] + qb[ct][3]);
      }
      unsigned w[4];
      #pragma unroll
      for (int d = 0; d < 4; ++d) {
        int srcl = ((lg & 1) * 2 + (d >> 1)) * 16 + l15;
        unsigned w0 = __shfl(pk[0][d & 1], srcl);
        unsigned w1 = __shfl(pk[1][d & 1], srcl);
        w[d] = (lane >= 32) ? w1 : w0;
      }
      uint4 u; u.x = w[0]; u.y = w[1]; u.z = w[2]; u.w = w[3];
      bqf[mt] = __builtin_bit_cast(bf16x8, u);
    }
  }

  __syncthreads();   // [2] all x reads done -> O may overlay xo_

  // ---- phase 2: attention; wave handles all 4 q-tiles of its head ----
  const float* blh = blut + wave * 4096;
  #pragma unroll
  for (int mi = 0; mi < 4; ++mi) {
    const int m0 = mi * 16;

    float psum = 0.f;
    bf16x4 pa4[4];                         // P^T fragments, in-lane
    #pragma unroll
    for (int nt = 0; nt < 4; ++nt) {
      f32x4 bias = *(const f32x4*)(blh + (m0 + l15) * 64 + nt * 16 + lg * 4);
      f32x4 z; z[0]=0.f; z[1]=0.f; z[2]=0.f; z[3]=0.f;
      f32x4 s = mfma32(akf[nt], bqf[mi], z);  // S^T[tok=nt*16+lg*4+i][q=m0+l15]
      float e0 = exp2f(s[0] + bias[0]);
      float e1 = exp2f(s[1] + bias[1]);
      float e2 = exp2f(s[2] + bias[2]);
      float e3 = exp2f(s[3] + bias[3]);
      psum += (e0 + e1) + (e2 + e3);
      uint2 pw; pw.x = pkbf(e0, e1); pw.y = pkbf(e2, e3);
      pa4[nt] = __builtin_bit_cast(bf16x4, pw);
    }
    psum += __shfl_xor(psum, 16);          // reduce over lg groups (same q column)
    psum += __shfl_xor(psum, 32);
    const float inv = __builtin_amdgcn_rcpf(psum);

    // PV as O^T = V^T * P^T, K=16 emulated (pa zero-padded, V dup-padded)
    f32x4 ot0, ot1;
    ot0[0]=0.f; ot0[1]=0.f; ot0[2]=0.f; ot0[3]=0.f;
    ot1[0]=0.f; ot1[1]=0.f; ot1[2]=0.f; ot1[3]=0.f;
    const __bf16* vrow0 = vTw + l15 * TSV;
    const __bf16* vrow1 = vrow0 + 16 * TSV;
    #pragma unroll
    for (int nt = 0; nt < 4; ++nt) {
      int tb = nt * 16 + lg * 4; if (tb > 48) tb = 48;
      bf16x8 pb8 = zpad8(pa4[nt]);
      bf16x4 v0 = *(const bf16x4*)(vrow0 + tb);
      bf16x4 v1 = *(const bf16x4*)(vrow1 + tb);
      ot0 = mfma32(dup8(v0), pb8, ot0);
      ot1 = mfma32(dup8(v1), pb8, ot1);
    }
    const int rq = m0 + l15;
    if (rq <= 48) {
      bf16x4 o4a, o4b;
      #pragma unroll
      for (int i = 0; i < 4; ++i) {
        o4a[i] = (__bf16)(ot0[i] * inv);
        o4b[i] = (__bf16)(ot1[i] * inv);
      }
      char* orow = xo_ + rq * (QS2 * 2);
      *(bf16x4*)(orow + (hc + lg * 4) * 2)      = o4a;  // b64 stores, 8B-aligned
      *(bf16x4*)(orow + (hc + 16 + lg * 4) * 2) = o4b;
    }
  }

  __syncthreads();   // [3] O ready across waves

  // ---- phase 3: proj GEMM; wave owns 32 output cols (2 ct tiles) ----
  bf16x8 bp[2][4];
  #pragma unroll
  for (int ct = 0; ct < 2; ++ct)
    #pragma unroll
    for (int kt = 0; kt < 4; ++kt)
      bp[ct][kt] = *(const bf16x8*)(projT + (hc + ct * 16 + l15) * CDIM + kt * 32 + lg * 8);
  float pbs[2];
  pbs[0] = proj_b[hc + l15];
  pbs[1] = proj_b[hc + 16 + l15];

  float* outw = out + (((b * 56) + wh * 7) * 56 + ww * 7) * CDIM;
  #pragma unroll
  for (int mt = 0; mt < 4; ++mt) {
    bf16x8 ao[4];
    #pragma unroll
    for (int kt = 0; kt < 4; ++kt)
      ao[kt] = *(const bf16x8*)(xo_ + rb[mt] + kt * 64 + lg * 16);
    #pragma unroll
    for (int ct = 0; ct < 2; ++ct) {
      f32x4 c0; c0[0]=0.f; c0[1]=0.f; c0[2]=0.f; c0[3]=0.f;
      #pragma unroll
      for (int kt = 0; kt < 4; ++kt) c0 = mfma32(ao[kt], bp[ct][kt], c0);
      #pragma unroll
      for (int i = 0; i < 4; ++i) {
        const int r = mt * 16 + lg * 4 + i;
        if (r < NTOK) {
          float* po = outw + ((r / 7) * 56 + (r % 7)) * CDIM + hc + ct * 16;
          po[l15] = c0[i] + pbs[ct];
        }
      }
    }
  }
}

extern "C" void kernel_launch(void* const* d_in, const int* in_sizes, int n_in,
                              void* d_out, int out_size, void* d_ws, size_t ws_size,
                              hipStream_t stream) {
  const float* x      = (const float*)d_in[0];
  const float* qkv_b  = (const float*)d_in[2];
  const float* proj_b = (const float*)d_in[4];

  hipLaunchKernelGGL(prep_kernel, dim3(320), dim3(256), 0, stream,
                     (const float*)d_in[1], (const float*)d_in[3], (const float*)d_in[5],
                     (__bf16*)d_ws, (__bf16*)((char*)d_ws + 98304),
                     (float*)((char*)d_ws + 131072));
  hipLaunchKernelGGL(attn_kernel, dim3(4096), dim3(256), 0, stream,
                     x, qkv_b, proj_b, (const char*)d_ws, (float*)d_out);
}